// Round 1
// baseline (6838.083 us; speedup 1.0000x reference)
//
#include <hip/hip_runtime.h>
#include <cmath>

// Leaky RNN:  h_t = 0.9 h_{t-1} + 0.1 tanh(h W_hh + u_t W_uh + b_h);  y_t = h_t W_hy + b_y
// B=64, T=2048, N_in=128, N_h=512, N_out=128.  Batch rows are independent -> one WG per row,
// no grid sync.  W_hh held in registers as f16 (128 VGPRs/thread), h broadcast via LDS f16 pairs,
// v_dot2_f32_f16 for 2 MAC/lane/cycle with fp32 accumulation.
//
// ws layout: U (f16, [B*T][512], 128 MiB) | H (f16, [B*T][512], 128 MiB).  Requires ws >= 256 MiB.

#define NB 64
#define NT 2048
#define NI 128
#define NH 512
#define NO 128

typedef unsigned short u16;
typedef _Float16 half2_t __attribute__((ext_vector_type(2)));

__device__ __forceinline__ float fdot2(half2_t a, half2_t b, float c) {
#if __has_builtin(__builtin_amdgcn_fdot2)
    return __builtin_amdgcn_fdot2(a, b, c, false);
#else
    return c + (float)a[0] * (float)b[0] + (float)a[1] * (float)b[1];
#endif
}

__device__ __forceinline__ u16 ftoh(float x) {
    return __builtin_bit_cast(u16, (_Float16)x);
}
__device__ __forceinline__ float htof(u16 x) {
    return (float)__builtin_bit_cast(_Float16, x);
}

// ---------------- Phase 1: U[m][n] = u[m][:] @ W_uh[:,n] + b_h[n]  (f16 out) ----------------
// M = NB*NT = 131072, K = 128, N = 512.  64x64 tiles, 256 threads (16x16), 4x4 per thread.
__global__ __launch_bounds__(256) void u_gemm(
        const float* __restrict__ A,    // u  [M][NI]
        const float* __restrict__ Bw,   // W_uh [NI][NH]
        const float* __restrict__ bh,   // [NH]
        u16* __restrict__ C) {          // U [M][NH] f16
    const int n0 = blockIdx.x * 64;
    const int m0 = blockIdx.y * 64;
    const int tid = threadIdx.x;
    const int tn = tid & 15, tm = tid >> 4;
    __shared__ float As[64][68];   // [k][m] transposed
    __shared__ float Bs[64][68];   // [k][n]
    float acc[4][4] = {};
    for (int k0 = 0; k0 < NI; k0 += 64) {
        const int r = tid >> 4, c4 = tid & 15;
        #pragma unroll
        for (int p = 0; p < 4; ++p) {
            const int row = r + p * 16;  // m-row in tile
            float4 v = *reinterpret_cast<const float4*>(&A[(size_t)(m0 + row) * NI + k0 + c4 * 4]);
            As[c4 * 4 + 0][row] = v.x; As[c4 * 4 + 1][row] = v.y;
            As[c4 * 4 + 2][row] = v.z; As[c4 * 4 + 3][row] = v.w;
        }
        #pragma unroll
        for (int p = 0; p < 4; ++p) {
            const int row = r + p * 16;  // k-row in tile
            float4 v = *reinterpret_cast<const float4*>(&Bw[(size_t)(k0 + row) * NH + n0 + c4 * 4]);
            *reinterpret_cast<float4*>(&Bs[row][c4 * 4]) = v;
        }
        __syncthreads();
        #pragma unroll
        for (int kk = 0; kk < 64; ++kk) {
            float4 av = *reinterpret_cast<const float4*>(&As[kk][tm * 4]);
            float4 bv = *reinterpret_cast<const float4*>(&Bs[kk][tn * 4]);
            const float am[4] = {av.x, av.y, av.z, av.w};
            const float bn[4] = {bv.x, bv.y, bv.z, bv.w};
            #pragma unroll
            for (int i = 0; i < 4; ++i)
                #pragma unroll
                for (int j = 0; j < 4; ++j)
                    acc[i][j] += am[i] * bn[j];
        }
        __syncthreads();
    }
    float bias[4];
    #pragma unroll
    for (int j = 0; j < 4; ++j) bias[j] = bh[n0 + tn * 4 + j];
    #pragma unroll
    for (int i = 0; i < 4; ++i) {
        const int m = m0 + tm * 4 + i;
        ushort4 out;
        out.x = ftoh(acc[i][0] + bias[0]);
        out.y = ftoh(acc[i][1] + bias[1]);
        out.z = ftoh(acc[i][2] + bias[2]);
        out.w = ftoh(acc[i][3] + bias[3]);
        *reinterpret_cast<ushort4*>(&C[(size_t)m * NH + n0 + tn * 4]) = out;
    }
}

// ---------------- Phase 2: sequential recurrence, one WG per batch row ----------------
// 1024 threads = 16 waves.  Wave w: k-chunk kc=w&3 (128 k's), columns jA=(w>>2)*128+l and jA+64.
// W_hh chunk in registers as 128 packed half2 (k-pairs).  h kept as f16 pairs in LDS (broadcast
// reads).  4-way k-chunk reduction through LDS.  2 barriers per step.
__global__ __launch_bounds__(1024) void rnn_seq(
        const float* __restrict__ Whh,   // [NH][NH]
        const float* __restrict__ h0,    // [NB][NH]
        const u16* __restrict__ U,       // [NB*NT][NH] f16
        u16* __restrict__ H) {           // [NB*NT][NH] f16 (out)
    const int b = blockIdx.x;
    const int tid = threadIdx.x;
    const int w = tid >> 6, l = tid & 63;
    const int kc = w & 3;                  // k in [kc*128, kc*128+128)
    const int jA = ((w >> 2) << 7) + l;    // columns jA, jA+64

    __shared__ __align__(16) unsigned int h2u[NH / 2];  // f16 pair (h[2p], h[2p+1])
    __shared__ float part[4][NH];

    // Load this thread's W_hh slice into registers (one-time, fully coalesced across lanes).
    half2_t wa[64], wb[64];
    const int k0 = kc << 7;
    #pragma unroll
    for (int p = 0; p < 64; ++p) {
        const float* base = &Whh[(size_t)(k0 + 2 * p) * NH];
        half2_t v0, v1;
        v0[0] = (_Float16)base[jA];       v0[1] = (_Float16)base[NH + jA];
        v1[0] = (_Float16)base[jA + 64];  v1[1] = (_Float16)base[NH + jA + 64];
        wa[p] = v0; wb[p] = v1;
    }

    float hreg = 0.f;
    if (tid < NH) hreg = h0[b * NH + tid];
    if (tid < NH / 2) {
        float2 hv = *reinterpret_cast<const float2*>(&h0[b * NH + 2 * tid]);
        half2_t hp; hp[0] = (_Float16)hv.x; hp[1] = (_Float16)hv.y;
        h2u[tid] = __builtin_bit_cast(unsigned int, hp);
    }
    __syncthreads();

    const u16* __restrict__ Urow = U + (size_t)b * NT * NH;
    u16* __restrict__ Hrow = H + (size_t)b * NT * NH;

    for (int t = 0; t < NT; ++t) {
        // issue U prefetch early; consumed after the dot phase (latency hidden under dot2s)
        float uval = 0.f;
        if (tid < NH) uval = htof(Urow[(size_t)t * NH + tid]);

        float acc0 = 0.f, acc1 = 0.f;
        const uint4* hp4 = reinterpret_cast<const uint4*>(&h2u[kc << 6]);
        #pragma unroll
        for (int q = 0; q < 16; ++q) {
            const uint4 hv = hp4[q];   // broadcast ds_read_b128 (all lanes same addr)
            const unsigned int hw[4] = {hv.x, hv.y, hv.z, hv.w};
            #pragma unroll
            for (int e = 0; e < 4; ++e) {
                const half2_t h2 = __builtin_bit_cast(half2_t, hw[e]);
                acc0 = fdot2(h2, wa[q * 4 + e], acc0);
                acc1 = fdot2(h2, wb[q * 4 + e], acc1);
            }
        }
        part[kc][jA] = acc0;
        part[kc][jA + 64] = acc1;
        __syncthreads();
        if (tid < NH) {
            const float pre = part[0][tid] + part[1][tid] + part[2][tid] + part[3][tid] + uval;
            hreg = 0.9f * hreg + 0.1f * tanhf(pre);
            const u16 hbits = ftoh(hreg);
            Hrow[(size_t)t * NH + tid] = hbits;             // streamed history (for y GEMM)
            reinterpret_cast<u16*>(h2u)[tid] = hbits;       // next step's broadcast source
        }
        __syncthreads();
    }
}

// ---------------- Phase 3: Y[m][n] = H[m][:] @ W_hy[:,n] + b_y[n]  (fp32 out) ----------------
// M = 131072, K = 512, N = 128.  64(m)x128(n) tiles, 256 threads (16x16), 4x8 per thread.
__global__ __launch_bounds__(256) void y_gemm(
        const u16* __restrict__ H,      // [M][NH] f16
        const float* __restrict__ Why,  // [NH][NO]
        const float* __restrict__ by,   // [NO]
        float* __restrict__ Y) {        // [M][NO]
    const int m0 = blockIdx.x * 64;
    const int tid = threadIdx.x;
    const int tn = tid & 15, tm = tid >> 4;
    __shared__ float As[64][68];    // [k][m] transposed
    __shared__ float Bs[64][132];   // [k][n]
    float acc[4][8] = {};
    for (int k0 = 0; k0 < NH; k0 += 64) {
        #pragma unroll
        for (int p = 0; p < 4; ++p) {
            const int idx = tid + p * 256;   // 1024 ushort4 slots
            const int r = idx >> 4;          // m-row
            const int c4 = idx & 15;         // k col4
            ushort4 v = *reinterpret_cast<const ushort4*>(&H[(size_t)(m0 + r) * NH + k0 + c4 * 4]);
            As[c4 * 4 + 0][r] = htof(v.x); As[c4 * 4 + 1][r] = htof(v.y);
            As[c4 * 4 + 2][r] = htof(v.z); As[c4 * 4 + 3][r] = htof(v.w);
        }
        #pragma unroll
        for (int p = 0; p < 8; ++p) {
            const int idx = tid + p * 256;   // 2048 float4 slots
            const int r = idx >> 5;          // k-row
            const int c4 = idx & 31;
            float4 v = *reinterpret_cast<const float4*>(&Why[(size_t)(k0 + r) * NO + c4 * 4]);
            *reinterpret_cast<float4*>(&Bs[r][c4 * 4]) = v;
        }
        __syncthreads();
        #pragma unroll
        for (int kk = 0; kk < 64; ++kk) {
            float4 av = *reinterpret_cast<const float4*>(&As[kk][tm * 4]);
            float4 b0 = *reinterpret_cast<const float4*>(&Bs[kk][tn * 8]);
            float4 b1 = *reinterpret_cast<const float4*>(&Bs[kk][tn * 8 + 4]);
            const float am[4] = {av.x, av.y, av.z, av.w};
            const float bn[8] = {b0.x, b0.y, b0.z, b0.w, b1.x, b1.y, b1.z, b1.w};
            #pragma unroll
            for (int i = 0; i < 4; ++i)
                #pragma unroll
                for (int j = 0; j < 8; ++j)
                    acc[i][j] += am[i] * bn[j];
        }
        __syncthreads();
    }
    float bias[8];
    #pragma unroll
    for (int j = 0; j < 8; ++j) bias[j] = by[tn * 8 + j];
    #pragma unroll
    for (int i = 0; i < 4; ++i) {
        const int m = m0 + tm * 4 + i;
        float4 o0, o1;
        o0.x = acc[i][0] + bias[0]; o0.y = acc[i][1] + bias[1];
        o0.z = acc[i][2] + bias[2]; o0.w = acc[i][3] + bias[3];
        o1.x = acc[i][4] + bias[4]; o1.y = acc[i][5] + bias[5];
        o1.z = acc[i][6] + bias[6]; o1.w = acc[i][7] + bias[7];
        *reinterpret_cast<float4*>(&Y[(size_t)m * NO + tn * 8]) = o0;
        *reinterpret_cast<float4*>(&Y[(size_t)m * NO + tn * 8 + 4]) = o1;
    }
}

extern "C" void kernel_launch(void* const* d_in, const int* in_sizes, int n_in,
                              void* d_out, int out_size, void* d_ws, size_t ws_size,
                              hipStream_t stream) {
    const float* u   = (const float*)d_in[0];   // [64][2048][128]
    const float* h0  = (const float*)d_in[1];   // [64][512]
    const float* Wuh = (const float*)d_in[2];   // [128][512]
    const float* Whh = (const float*)d_in[3];   // [512][512]
    const float* Why = (const float*)d_in[4];   // [512][128]
    const float* bh  = (const float*)d_in[5];   // [512]
    const float* by  = (const float*)d_in[6];   // [128]
    float* y = (float*)d_out;                   // [64][2048][128]

    u16* Uws = (u16*)d_ws;                       // 67,108,864 f16 = 128 MiB
    u16* Hws = Uws + (size_t)NB * NT * NH;       // 128 MiB
    (void)in_sizes; (void)n_in; (void)out_size; (void)ws_size;

    u_gemm<<<dim3(NH / 64, (NB * NT) / 64), 256, 0, stream>>>(u, Wuh, bh, Uws);
    rnn_seq<<<dim3(NB), 1024, 0, stream>>>(Whh, h0, Uws, Hws);
    y_gemm<<<dim3((NB * NT) / 64), 256, 0, stream>>>(Hws, Why, by, y);
}

// Round 2
// 6319.938 us; speedup vs baseline: 1.0820x; 1.0820x over previous
//
#include <hip/hip_runtime.h>
#include <cmath>

// Leaky RNN:  h_t = 0.9 h_{t-1} + 0.1 tanh(h W_hh + u_t W_uh + b_h);  y_t = h_t W_hy + b_y
// B=64, T=2048, N_in=128, N_h=512, N_out=128.
//
// Phase 2 structure (the critical path): one WG per batch row (64 WGs), 1024 threads.
// f16 W_hh = 512 KB = 100% of a CU's VGPR file, so full register residency is impossible.
// Each thread owns 2 columns x 128 k: column A's weights (64 half2 = 64 VGPR) are STATIC
// in registers; column B's weights are STREAMED each step from a pre-packed f16 buffer
// (L2-resident, 256 KB/CU/step) with double-buffered dwordx4 loads. v_dot2_f32_f16 for
// the MACs, fp32 accumulation, h broadcast via LDS f16 pairs.
//
// ws layout: U (f16 [B*T][512], 128 MiB) | H (f16 [B*T][512], 128 MiB).
// Wpk (256 KiB) lives in d_out, which is dead until y_gemm overwrites it at the end.

#define NB 64
#define NT 2048
#define NI 128
#define NH 512
#define NO 128

typedef unsigned short u16;
typedef _Float16 half2_t __attribute__((ext_vector_type(2)));

__device__ __forceinline__ float fdot2(half2_t a, half2_t b, float c) {
#if __has_builtin(__builtin_amdgcn_fdot2)
    return __builtin_amdgcn_fdot2(a, b, c, false);
#else
    return c + (float)a[0] * (float)b[0] + (float)a[1] * (float)b[1];
#endif
}

__device__ __forceinline__ u16 ftoh(float x) {
    return __builtin_bit_cast(u16, (_Float16)x);
}
__device__ __forceinline__ float htof(u16 x) {
    return (float)__builtin_bit_cast(_Float16, x);
}

// ---------------- Phase 0: pack the streamed half of W_hh into f16, load-order layout ----
// Thread (w,l) streams column jB=(w>>2)*128+l+64, k-chunk kc=w&3.  Load c,q is a dwordx4
// holding k-pairs p = c*16+q*4+{0..3} (k = kc*128+2p).  Layout idx = ((w*4+c)*4+q)*64+l.
__global__ __launch_bounds__(256) void wpack(const float* __restrict__ Whh,
                                             uint4* __restrict__ Wpk) {
    const int idx = blockIdx.x * 256 + threadIdx.x;   // 0..16383
    const int l = idx & 63, q = (idx >> 6) & 3, c = (idx >> 8) & 3, w = idx >> 10;
    const int kc = w & 3;
    const int jB = ((w >> 2) << 7) + l + 64;
    const int pbase = c * 16 + q * 4;
    unsigned int r[4];
    #pragma unroll
    for (int j = 0; j < 4; ++j) {
        const int k = (kc << 7) + 2 * (pbase + j);
        half2_t v;
        v[0] = (_Float16)Whh[(size_t)k * NH + jB];
        v[1] = (_Float16)Whh[(size_t)(k + 1) * NH + jB];
        r[j] = __builtin_bit_cast(unsigned int, v);
    }
    uint4 o; o.x = r[0]; o.y = r[1]; o.z = r[2]; o.w = r[3];
    Wpk[idx] = o;
}

// ---------------- Phase 1: U[m][n] = u[m][:] @ W_uh[:,n] + b_h[n]  (f16 out) ----------------
__global__ __launch_bounds__(256) void u_gemm(
        const float* __restrict__ A,    // u  [M][NI]
        const float* __restrict__ Bw,   // W_uh [NI][NH]
        const float* __restrict__ bh,   // [NH]
        u16* __restrict__ C) {          // U [M][NH] f16
    const int n0 = blockIdx.x * 64;
    const int m0 = blockIdx.y * 64;
    const int tid = threadIdx.x;
    const int tn = tid & 15, tm = tid >> 4;
    __shared__ float As[64][68];   // [k][m] transposed
    __shared__ float Bs[64][68];   // [k][n]
    float acc[4][4] = {};
    for (int k0 = 0; k0 < NI; k0 += 64) {
        const int r = tid >> 4, c4 = tid & 15;
        #pragma unroll
        for (int p = 0; p < 4; ++p) {
            const int row = r + p * 16;
            float4 v = *reinterpret_cast<const float4*>(&A[(size_t)(m0 + row) * NI + k0 + c4 * 4]);
            As[c4 * 4 + 0][row] = v.x; As[c4 * 4 + 1][row] = v.y;
            As[c4 * 4 + 2][row] = v.z; As[c4 * 4 + 3][row] = v.w;
        }
        #pragma unroll
        for (int p = 0; p < 4; ++p) {
            const int row = r + p * 16;
            float4 v = *reinterpret_cast<const float4*>(&Bw[(size_t)(k0 + row) * NH + n0 + c4 * 4]);
            *reinterpret_cast<float4*>(&Bs[row][c4 * 4]) = v;
        }
        __syncthreads();
        #pragma unroll
        for (int kk = 0; kk < 64; ++kk) {
            float4 av = *reinterpret_cast<const float4*>(&As[kk][tm * 4]);
            float4 bv = *reinterpret_cast<const float4*>(&Bs[kk][tn * 4]);
            const float am[4] = {av.x, av.y, av.z, av.w};
            const float bn[4] = {bv.x, bv.y, bv.z, bv.w};
            #pragma unroll
            for (int i = 0; i < 4; ++i)
                #pragma unroll
                for (int j = 0; j < 4; ++j)
                    acc[i][j] += am[i] * bn[j];
        }
        __syncthreads();
    }
    float bias[4];
    #pragma unroll
    for (int j = 0; j < 4; ++j) bias[j] = bh[n0 + tn * 4 + j];
    #pragma unroll
    for (int i = 0; i < 4; ++i) {
        const int m = m0 + tm * 4 + i;
        ushort4 out;
        out.x = ftoh(acc[i][0] + bias[0]);
        out.y = ftoh(acc[i][1] + bias[1]);
        out.z = ftoh(acc[i][2] + bias[2]);
        out.w = ftoh(acc[i][3] + bias[3]);
        *reinterpret_cast<ushort4*>(&C[(size_t)m * NH + n0 + tn * 4]) = out;
    }
}

// ---------------- Phase 2: sequential recurrence ----------------
// 1024 threads = 16 waves.  Wave w: k-chunk kc=w&3, lane l: cols jA=(w>>2)*128+l (static
// registers) and jA+64 (streamed).  4-way k-chunk reduction through LDS.  2 barriers/step.
__global__ __launch_bounds__(1024, 4) void rnn_seq(
        const float* __restrict__ Whh,   // [NH][NH] fp32 (for the one-time static load)
        const float* __restrict__ h0,    // [NB][NH]
        const u16* __restrict__ U,       // [NB*NT][NH] f16
        u16* __restrict__ H,             // [NB*NT][NH] f16 (out)
        const uint4* __restrict__ Wpk) { // packed streamed half, 16384 uint4
    const int b = blockIdx.x;
    const int tid = threadIdx.x;
    const int w = tid >> 6, l = tid & 63;
    const int kc = w & 3;
    const int jA = ((w >> 2) << 7) + l;

    __shared__ __align__(16) unsigned int h2u[NH / 2];
    __shared__ float part[4][NH];

    // One-time static load: column jA, k-chunk kc (coalesced across lanes).
    half2_t wa[64];
    const int k0 = kc << 7;
    #pragma unroll
    for (int p = 0; p < 64; ++p) {
        const float* base = &Whh[(size_t)(k0 + 2 * p) * NH + jA];
        half2_t v; v[0] = (_Float16)base[0]; v[1] = (_Float16)base[NH];
        wa[p] = v;
    }

    float hreg = 0.f;
    if (tid < NH) hreg = h0[b * NH + tid];
    if (tid < NH / 2) {
        float2 hv = *reinterpret_cast<const float2*>(&h0[b * NH + 2 * tid]);
        half2_t hp; hp[0] = (_Float16)hv.x; hp[1] = (_Float16)hv.y;
        h2u[tid] = __builtin_bit_cast(unsigned int, hp);
    }
    __syncthreads();

    const u16* __restrict__ Urow = U + (size_t)b * NT * NH;
    u16* __restrict__ Hrow = H + (size_t)b * NT * NH;
    const uint4* __restrict__ wbase = Wpk + (size_t)w * 1024 + l;   // + (c*4+q)*64
    const uint4* __restrict__ hb4 = reinterpret_cast<const uint4*>(&h2u[kc << 6]);

    uint4 bufA[4], bufB[4];

    for (int t = 0; t < NT; ++t) {
        // U prefetch (raw bits; converted after the dot phase)
        u16 ubits = 0;
        if (tid < NH) ubits = Urow[(size_t)t * NH + tid];

        // chunk 0 loads
        #pragma unroll
        for (int q = 0; q < 4; ++q) bufA[q] = wbase[q * 64];

        float acc0 = 0.f, acc1 = 0.f;
        #pragma unroll
        for (int c = 0; c < 4; ++c) {
            uint4* cur = (c & 1) ? bufB : bufA;
            uint4* nxt = (c & 1) ? bufA : bufB;
            if (c < 3) {
                #pragma unroll
                for (int q = 0; q < 4; ++q) nxt[q] = wbase[((c + 1) * 4 + q) * 64];
            }
            #pragma unroll
            for (int qq = 0; qq < 2; ++qq) {
                uint4 h0q = hb4[c * 4 + 2 * qq];       // broadcast ds_read_b128
                uint4 h1q = hb4[c * 4 + 2 * qq + 1];
                const unsigned int hw[8] = {h0q.x, h0q.y, h0q.z, h0q.w,
                                            h1q.x, h1q.y, h1q.z, h1q.w};
                const uint4 w0 = cur[2 * qq], w1 = cur[2 * qq + 1];
                const unsigned int ww[8] = {w0.x, w0.y, w0.z, w0.w,
                                            w1.x, w1.y, w1.z, w1.w};
                #pragma unroll
                for (int j = 0; j < 8; ++j) {
                    const half2_t h2 = __builtin_bit_cast(half2_t, hw[j]);
                    acc0 = fdot2(h2, wa[c * 16 + qq * 8 + j], acc0);
                    acc1 = fdot2(h2, __builtin_bit_cast(half2_t, ww[j]), acc1);
                }
            }
        }
        part[kc][jA] = acc0;
        part[kc][jA + 64] = acc1;
        __syncthreads();
        if (tid < NH) {
            const float pre = part[0][tid] + part[1][tid] + part[2][tid] + part[3][tid]
                              + htof(ubits);
            // tanh(x) = 1 - 2/(e^{2x}+1); saturates correctly at +-inf
            const float e = __expf(2.f * pre);
            const float th = 1.f - 2.f / (e + 1.f);
            hreg = 0.9f * hreg + 0.1f * th;
            const u16 hb = ftoh(hreg);
            Hrow[(size_t)t * NH + tid] = hb;
            reinterpret_cast<u16*>(h2u)[tid] = hb;
        }
        __syncthreads();
    }
}

// ---------------- Phase 3: Y[m][n] = H[m][:] @ W_hy[:,n] + b_y[n]  (fp32 out) ----------------
__global__ __launch_bounds__(256) void y_gemm(
        const u16* __restrict__ H,      // [M][NH] f16
        const float* __restrict__ Why,  // [NH][NO]
        const float* __restrict__ by,   // [NO]
        float* __restrict__ Y) {        // [M][NO]
    const int m0 = blockIdx.x * 64;
    const int tid = threadIdx.x;
    const int tn = tid & 15, tm = tid >> 4;
    __shared__ float As[64][68];    // [k][m] transposed
    __shared__ float Bs[64][132];   // [k][n]
    float acc[4][8] = {};
    for (int k0 = 0; k0 < NH; k0 += 64) {
        #pragma unroll
        for (int p = 0; p < 4; ++p) {
            const int idx = tid + p * 256;
            const int r = idx >> 4;
            const int c4 = idx & 15;
            ushort4 v = *reinterpret_cast<const ushort4*>(&H[(size_t)(m0 + r) * NH + k0 + c4 * 4]);
            As[c4 * 4 + 0][r] = htof(v.x); As[c4 * 4 + 1][r] = htof(v.y);
            As[c4 * 4 + 2][r] = htof(v.z); As[c4 * 4 + 3][r] = htof(v.w);
        }
        #pragma unroll
        for (int p = 0; p < 8; ++p) {
            const int idx = tid + p * 256;
            const int r = idx >> 5;
            const int c4 = idx & 31;
            float4 v = *reinterpret_cast<const float4*>(&Why[(size_t)(k0 + r) * NO + c4 * 4]);
            *reinterpret_cast<float4*>(&Bs[r][c4 * 4]) = v;
        }
        __syncthreads();
        #pragma unroll
        for (int kk = 0; kk < 64; ++kk) {
            float4 av = *reinterpret_cast<const float4*>(&As[kk][tm * 4]);
            float4 b0 = *reinterpret_cast<const float4*>(&Bs[kk][tn * 8]);
            float4 b1 = *reinterpret_cast<const float4*>(&Bs[kk][tn * 8 + 4]);
            const float am[4] = {av.x, av.y, av.z, av.w};
            const float bn[8] = {b0.x, b0.y, b0.z, b0.w, b1.x, b1.y, b1.z, b1.w};
            #pragma unroll
            for (int i = 0; i < 4; ++i)
                #pragma unroll
                for (int j = 0; j < 8; ++j)
                    acc[i][j] += am[i] * bn[j];
        }
        __syncthreads();
    }
    float bias[8];
    #pragma unroll
    for (int j = 0; j < 8; ++j) bias[j] = by[tn * 8 + j];
    #pragma unroll
    for (int i = 0; i < 4; ++i) {
        const int m = m0 + tm * 4 + i;
        float4 o0, o1;
        o0.x = acc[i][0] + bias[0]; o0.y = acc[i][1] + bias[1];
        o0.z = acc[i][2] + bias[2]; o0.w = acc[i][3] + bias[3];
        o1.x = acc[i][4] + bias[4]; o1.y = acc[i][5] + bias[5];
        o1.z = acc[i][6] + bias[6]; o1.w = acc[i][7] + bias[7];
        *reinterpret_cast<float4*>(&Y[(size_t)m * NO + tn * 8]) = o0;
        *reinterpret_cast<float4*>(&Y[(size_t)m * NO + tn * 8 + 4]) = o1;
    }
}

extern "C" void kernel_launch(void* const* d_in, const int* in_sizes, int n_in,
                              void* d_out, int out_size, void* d_ws, size_t ws_size,
                              hipStream_t stream) {
    const float* u   = (const float*)d_in[0];   // [64][2048][128]
    const float* h0  = (const float*)d_in[1];   // [64][512]
    const float* Wuh = (const float*)d_in[2];   // [128][512]
    const float* Whh = (const float*)d_in[3];   // [512][512]
    const float* Why = (const float*)d_in[4];   // [512][128]
    const float* bh  = (const float*)d_in[5];   // [512]
    const float* by  = (const float*)d_in[6];   // [128]
    float* y = (float*)d_out;                   // [64][2048][128] fp32

    u16* Uws = (u16*)d_ws;                       // 128 MiB
    u16* Hws = Uws + (size_t)NB * NT * NH;       // 128 MiB
    // Streamed-W pack buffer lives in d_out (64 MiB fp32) — dead until y_gemm runs last.
    uint4* Wpk = (uint4*)d_out;                  // 256 KiB
    (void)in_sizes; (void)n_in; (void)out_size; (void)ws_size;

    wpack<<<dim3(64), 256, 0, stream>>>(Whh, Wpk);
    u_gemm<<<dim3(NH / 64, (NB * NT) / 64), 256, 0, stream>>>(u, Wuh, bh, Uws);
    rnn_seq<<<dim3(NB), 1024, 0, stream>>>(Whh, h0, Uws, Hws, Wpk);
    y_gemm<<<dim3((NB * NT) / 64), 256, 0, stream>>>(Hws, Why, by, y);
}